// Round 1
// baseline (16483.376 us; speedup 1.0000x reference)
//
#include <hip/hip_runtime.h>

// PositionCloser: 1024 independent LSTM sequences (hid=64), 16384 sequential
// steps each. Mapping: 1 sequence = 1 wave (64 lanes) = 1 SIMD; 1024 waves
// fill all 256 CUs x 4 SIMDs exactly once. W_hh lives in 256 VGPRs/lane
// (lane k holds gate rows k, 64+k, 128+k, 192+k). h broadcast via v_readlane.

#define B2i   16
#define CHUNKi 128
#define HIDi  64

__device__ __forceinline__ float rl(float v, int lane) {
  return __builtin_bit_cast(float, __builtin_amdgcn_readlane(__builtin_bit_cast(int, v), lane));
}
__device__ __forceinline__ float frcp(float x) { return __builtin_amdgcn_rcpf(x); }
// sigmoid(x) = 1/(1+e^-x); safe at both extremes (exp->inf => rcp->0; exp->0 => 1)
__device__ __forceinline__ float sigm(float x) { return frcp(1.0f + __expf(-x)); }
// tanh(x) = 1 - 2/(e^{2x}+1); safe at both extremes (never forms inf*0)
__device__ __forceinline__ float tanh_(float x) {
  float e = __expf(2.0f * x);
  return 1.0f - 2.0f * frcp(e + 1.0f);
}

__global__ __launch_bounds__(64, 1)
void pc_lstm_kernel(const int* __restrict__ inds,
                    const float* __restrict__ p,
                    const float* __restrict__ ls_probs,
                    const float* __restrict__ open_probs,
                    const int* __restrict__ open_slices,
                    const float* __restrict__ open_hx,
                    const float* __restrict__ W_ih,
                    const float* __restrict__ W_hh,
                    const float* __restrict__ b_ih,
                    const float* __restrict__ b_hh,
                    const float* __restrict__ W_out,
                    const float* __restrict__ b_out,
                    const int* __restrict__ n_chunks_p,
                    float* __restrict__ out)
{
  const int lane = threadIdx.x;      // 0..63
  const int s    = blockIdx.x;       // 0..1023  (sequence id = bi*16 + bj)
  const int bi   = s >> 4;
  const int bj   = s & 15;
  const int n_chunks = n_chunks_p[0];

  // ---- per-lane recurrent weights: 4 gate rows x 64 cols, 256 VGPRs ----
  float W0[HIDi], W1[HIDi], W2[HIDi], W3[HIDi];
  {
    const float* r0 = W_hh + (0 * HIDi + lane) * HIDi;
    const float* r1 = W_hh + (1 * HIDi + lane) * HIDi;
    const float* r2 = W_hh + (2 * HIDi + lane) * HIDi;
    const float* r3 = W_hh + (3 * HIDi + lane) * HIDi;
#pragma unroll
    for (int j4 = 0; j4 < HIDi; j4 += 4) {
      float4 v0 = *(const float4*)(r0 + j4);
      float4 v1 = *(const float4*)(r1 + j4);
      float4 v2 = *(const float4*)(r2 + j4);
      float4 v3 = *(const float4*)(r3 + j4);
      W0[j4] = v0.x; W0[j4+1] = v0.y; W0[j4+2] = v0.z; W0[j4+3] = v0.w;
      W1[j4] = v1.x; W1[j4+1] = v1.y; W1[j4+2] = v1.z; W1[j4+3] = v1.w;
      W2[j4] = v2.x; W2[j4+1] = v2.y; W2[j4+2] = v2.z; W2[j4+3] = v2.w;
      W3[j4] = v3.x; W3[j4+1] = v3.y; W3[j4+2] = v3.z; W3[j4+3] = v3.w;
    }
  }

  // input weights + fused bias for this lane's 4 gate rows
  float wx0[4], wx1[4], bs[4];
#pragma unroll
  for (int g = 0; g < 4; ++g) {
    int r = g * HIDi + lane;
    wx0[g] = W_ih[2 * r];
    wx1[g] = W_ih[2 * r + 1];
    bs[g]  = b_ih[r] + b_hh[r];
  }
  const float wout = W_out[lane];
  const float bout = b_out[0];

  // ---- per-sequence state ----
  const int sb = bi * B2i + bj;
  float h = open_hx[(sb * 2 + 0) * HIDi + lane];
  float c = open_hx[(sb * 2 + 1) * HIDi + lane];
  const int os = open_slices[sb];
  const float OL = __logf(p[2 * os]) + __logf(p[2 * os + 1]);
  const float ls = ls_probs[sb];
  const float op = open_probs[sb];
  const float coef = op * (2.0f * ls - 1.0f);   // payoff collapses to coef*(L_t - OL)
  const int tbase = inds[bi] + bj;

  float S = 1.0f;       // last_nd carried across chunks
  float D = 1.0f;       // running not_done within a chunk
  float loss = 0.0f;

  const float2* p2 = (const float2*)p;
  // preload chunk 0 prices: lane holds t=lane and t=64+lane
  float2 curA = p2[tbase + lane];
  float2 curB = p2[tbase + HIDi + lane];

  for (int off = 0; off < n_chunks; ++off) {
    // prefetch next chunk while this one computes (~110K cycles of cover)
    float2 nxtA = curA, nxtB = curB;
    if (off + 1 < n_chunks) {
      int nb = tbase + (off + 1) * CHUNKi;
      nxtA = p2[nb + lane];
      nxtB = p2[nb + HIDi + lane];
    }
    const float LA = __logf(curA.x) + __logf(curA.y);   // L_t for t=lane
    const float LB = __logf(curB.x) + __logf(curB.y);   // L_t for t=64+lane
    const float px0 = rl(curA.x, 0);                    // chunk-base price
    const float px1 = rl(curA.y, 0);

#pragma unroll 1
    for (int tt = 0; tt < CHUNKi; ++tt) {
      const int tl = tt & 63;
      float sp0, sp1, Lt;
      if (tt < HIDi) { sp0 = rl(curA.x, tl); sp1 = rl(curA.y, tl); Lt = rl(LA, tl); }
      else           { sp0 = rl(curB.x, tl); sp1 = rl(curB.y, tl); Lt = rl(LB, tl); }

      const float x0 = sp0 - px0;
      const float x1 = sp1 - px1;
      float a0 = fmaf(x1, wx1[0], fmaf(x0, wx0[0], bs[0]));
      float a1 = fmaf(x1, wx1[1], fmaf(x0, wx0[1], bs[1]));
      float a2 = fmaf(x1, wx1[2], fmaf(x0, wx0[2], bs[2]));
      float a3 = fmaf(x1, wx1[3], fmaf(x0, wx0[3], bs[3]));

      // g = xg_t + h @ W_hh.T  : broadcast h_j via readlane, 4 FMA per j
#pragma unroll
      for (int jj = 0; jj < HIDi; ++jj) {
        const float hj = rl(h, jj);
        a0 = fmaf(hj, W0[jj], a0);
        a1 = fmaf(hj, W1[jj], a1);
        a2 = fmaf(hj, W2[jj], a2);
        a3 = fmaf(hj, W3[jj], a3);
      }

      const float ig = sigm(a0);
      const float fg = sigm(a1);
      const float gg = tanh_(a2);
      const float og = sigm(a3);
      c = fmaf(fg, c, ig * gg);
      h = og * tanh_(c);

      // z = h . W_out + b_out  (wave reduction -> uniform across lanes)
      float zp = h * wout;
#pragma unroll
      for (int m = 32; m > 0; m >>= 1) zp += __shfl_xor(zp, m, 64);
      const float probs = sigm(zp + bout);

      // reference quirk: chunk-local t=0 prob is NOT discounted by last_nd
      const float pn = (tt == 0) ? probs : probs * D;
      loss = fmaf(coef * pn, Lt - OL, loss);

      if (tt == 0)              D = S * (1.0f - probs);
      else if (tt < CHUNKi - 1) D *= (1.0f - probs);
      else                      S = D;   // last step's (1-p) excluded from carry
    }

    curA = nxtA;
    curB = nxtB;
  }

  if (lane == 0) atomicAdd(out, loss);
}

extern "C" void kernel_launch(void* const* d_in, const int* in_sizes, int n_in,
                              void* d_out, int out_size, void* d_ws, size_t ws_size,
                              hipStream_t stream) {
  // d_out is re-poisoned to 0xAA before every timed launch: zero it ourselves.
  hipMemsetAsync(d_out, 0, sizeof(float), stream);

  pc_lstm_kernel<<<dim3(64 * 16), dim3(64), 0, stream>>>(
      (const int*)d_in[0],    // inds
      (const float*)d_in[1],  // p
      (const float*)d_in[2],  // ls_probs
      (const float*)d_in[3],  // open_probs
      (const int*)d_in[4],    // open_slices
      (const float*)d_in[5],  // open_hx
      (const float*)d_in[6],  // W_ih
      (const float*)d_in[7],  // W_hh
      (const float*)d_in[8],  // b_ih
      (const float*)d_in[9],  // b_hh
      (const float*)d_in[10], // W_out
      (const float*)d_in[11], // b_out
      (const int*)d_in[12],   // n_chunks
      (float*)d_out);
}

// Round 3
// 9281.122 us; speedup vs baseline: 1.7760x; 1.7760x over previous
//
#include <hip/hip_runtime.h>

// PositionCloser: 1024 independent LSTM sequences (hid=64), 16384 sequential
// steps each. 1 sequence = 1 wave = 1 SIMD (1024 waves fill the chip exactly).
// Round 3: same as round 2 (W_hh packed f16x2 in 128 arch VGPRs, matvec via
// v_dot2_f32_f16), with half2v typedef fixed to __fp16 (builtin return type).

#define B2i    16
#define CHUNKi 128
#define HIDi   64

typedef __fp16 half2v __attribute__((ext_vector_type(2)));

__device__ __forceinline__ float rlf(float v, int lane) {
  return __builtin_bit_cast(float, __builtin_amdgcn_readlane(__builtin_bit_cast(int, v), lane));
}
__device__ __forceinline__ half2v rlh2(half2v v, int lane) {
  return __builtin_bit_cast(half2v, __builtin_amdgcn_readlane(__builtin_bit_cast(int, v), lane));
}
__device__ __forceinline__ float frcp(float x) { return __builtin_amdgcn_rcpf(x); }
// sigmoid(x) = 1/(1+e^-x); safe at both extremes
__device__ __forceinline__ float sigm(float x) { return frcp(1.0f + __expf(-x)); }
// tanh(x) = 1 - 2/(e^{2x}+1); safe at both extremes
__device__ __forceinline__ float tanh_(float x) {
  float e = __expf(2.0f * x);
  return 1.0f - 2.0f * frcp(e + 1.0f);
}

__global__ __launch_bounds__(64, 1)
void pc_lstm_kernel(const int* __restrict__ inds,
                    const float* __restrict__ p,
                    const float* __restrict__ ls_probs,
                    const float* __restrict__ open_probs,
                    const int* __restrict__ open_slices,
                    const float* __restrict__ open_hx,
                    const float* __restrict__ W_ih,
                    const float* __restrict__ W_hh,
                    const float* __restrict__ b_ih,
                    const float* __restrict__ b_hh,
                    const float* __restrict__ W_out,
                    const float* __restrict__ b_out,
                    const int* __restrict__ n_chunks_p,
                    float* __restrict__ out)
{
  const int lane = threadIdx.x;      // 0..63
  const int s    = blockIdx.x;       // 0..1023
  const int bi   = s >> 4;
  const int bj   = s & 15;
  const int n_chunks = n_chunks_p[0];

  // ---- recurrent weights: 4 gate rows x 64 cols, packed f16x2 -> 128 VGPRs
  half2v W0[HIDi / 2], W1[HIDi / 2], W2[HIDi / 2], W3[HIDi / 2];
  {
    const float2* r0 = (const float2*)(W_hh + (0 * HIDi + lane) * HIDi);
    const float2* r1 = (const float2*)(W_hh + (1 * HIDi + lane) * HIDi);
    const float2* r2 = (const float2*)(W_hh + (2 * HIDi + lane) * HIDi);
    const float2* r3 = (const float2*)(W_hh + (3 * HIDi + lane) * HIDi);
#pragma unroll
    for (int j = 0; j < HIDi / 2; ++j) {
      float2 v0 = r0[j], v1 = r1[j], v2 = r2[j], v3 = r3[j];
      W0[j] = __builtin_amdgcn_cvt_pkrtz(v0.x, v0.y);
      W1[j] = __builtin_amdgcn_cvt_pkrtz(v1.x, v1.y);
      W2[j] = __builtin_amdgcn_cvt_pkrtz(v2.x, v2.y);
      W3[j] = __builtin_amdgcn_cvt_pkrtz(v3.x, v3.y);
    }
  }

  // input weights + fused bias for this lane's 4 gate rows (f32)
  float wx0[4], wx1[4], bs[4];
#pragma unroll
  for (int g = 0; g < 4; ++g) {
    int r = g * HIDi + lane;
    wx0[g] = W_ih[2 * r];
    wx1[g] = W_ih[2 * r + 1];
    bs[g]  = b_ih[r] + b_hh[r];
  }
  const float wout = W_out[lane];
  const float bout = b_out[0];

  // ---- per-sequence state ----
  const int sb = bi * B2i + bj;
  float h = open_hx[(sb * 2 + 0) * HIDi + lane];
  float c = open_hx[(sb * 2 + 1) * HIDi + lane];
  const int os = open_slices[sb];
  const float OL = __logf(p[2 * os]) + __logf(p[2 * os + 1]);
  const float ls = ls_probs[sb];
  const float op = open_probs[sb];
  const float coef = op * (2.0f * ls - 1.0f);   // payoff = coef*(L_t - OL)
  const int tbase = inds[bi] + bj;

  float S = 1.0f;       // last_nd carried across chunks
  float lsum = 0.0f;    // sum pn * L_t
  float psum = 0.0f;    // sum pn

  const float2* p2 = (const float2*)p;
  float2 curA = p2[tbase + lane];          // t = lane
  float2 curB = p2[tbase + HIDi + lane];   // t = 64 + lane

  for (int off = 0; off < n_chunks; ++off) {
    float2 nxtA = curA, nxtB = curB;
    if (off + 1 < n_chunks) {
      int nb = tbase + (off + 1) * CHUNKi;
      nxtA = p2[nb + lane];
      nxtB = p2[nb + HIDi + lane];
    }
    const float LA = __logf(curA.x) + __logf(curA.y);
    const float LB = __logf(curB.x) + __logf(curB.y);
    const float px0 = rlf(curA.x, 0);
    const float px1 = rlf(curA.y, 0);

    float Q = 1.0f;     // running cumprod of (1-p) within the chunk

#pragma unroll 1
    for (int hf = 0; hf < 2; ++hf) {
      const float sx = hf ? curB.x : curA.x;
      const float sy = hf ? curB.y : curA.y;
      const float Lh = hf ? LB : LA;
#pragma unroll 2
      for (int tt = 0; tt < HIDi; ++tt) {
        const int t = (hf << 6) + tt;
        const float sp0 = rlf(sx, tt);
        const float sp1 = rlf(sy, tt);
        const float Lt  = rlf(Lh, tt);

        // pack h into f16 pairs: even lane 2j holds (h_2j, h_2j+1)
        const float hpart = __shfl_xor(h, 1, 64);
        const half2v hpk = __builtin_amdgcn_cvt_pkrtz(h, hpart);

        float a0 = bs[0], a1 = bs[1], a2 = bs[2], a3 = bs[3];
#pragma unroll
        for (int j = 0; j < HIDi / 2; ++j) {
          const half2v hj = rlh2(hpk, 2 * j);
          a0 = __builtin_amdgcn_fdot2(hj, W0[j], a0, false);
          a1 = __builtin_amdgcn_fdot2(hj, W1[j], a1, false);
          a2 = __builtin_amdgcn_fdot2(hj, W2[j], a2, false);
          a3 = __builtin_amdgcn_fdot2(hj, W3[j], a3, false);
        }
        // input contribution (f32), off the h-dependent critical path
        const float x0 = sp0 - px0;
        const float x1 = sp1 - px1;
        a0 += fmaf(x1, wx1[0], x0 * wx0[0]);
        a1 += fmaf(x1, wx1[1], x0 * wx0[1]);
        a2 += fmaf(x1, wx1[2], x0 * wx0[2]);
        a3 += fmaf(x1, wx1[3], x0 * wx0[3]);

        const float ig = sigm(a0);
        const float fg = sigm(a1);
        const float gg = tanh_(a2);
        const float og = sigm(a3);
        c = fmaf(fg, c, ig * gg);
        h = og * tanh_(c);

        // z = h . W_out + b_out (wave reduction -> uniform)
        float zp = h * wout;
#pragma unroll
        for (int m = 32; m > 0; m >>= 1) zp += __shfl_xor(zp, m, 64);
        const float probs = sigm(zp + bout);

        // reference quirk: chunk-local t=0 prob is NOT discounted by last_nd
        const float T  = (t == 0) ? 1.0f : S * Q;
        const float pn = probs * T;
        lsum = fmaf(pn, Lt, lsum);
        psum += pn;
        if (t == CHUNKi - 1) S = S * Q;        // last_nd excludes (1-p_127)
        Q = Q * (1.0f - probs);
      }
    }

    curA = nxtA;
    curB = nxtB;
  }

  if (lane == 0) atomicAdd(out, coef * (lsum - OL * psum));
}

extern "C" void kernel_launch(void* const* d_in, const int* in_sizes, int n_in,
                              void* d_out, int out_size, void* d_ws, size_t ws_size,
                              hipStream_t stream) {
  (void)hipMemsetAsync(d_out, 0, sizeof(float), stream);

  pc_lstm_kernel<<<dim3(64 * 16), dim3(64), 0, stream>>>(
      (const int*)d_in[0],    // inds
      (const float*)d_in[1],  // p
      (const float*)d_in[2],  // ls_probs
      (const float*)d_in[3],  // open_probs
      (const int*)d_in[4],    // open_slices
      (const float*)d_in[5],  // open_hx
      (const float*)d_in[6],  // W_ih
      (const float*)d_in[7],  // W_hh
      (const float*)d_in[8],  // b_ih
      (const float*)d_in[9],  // b_hh
      (const float*)d_in[10], // W_out
      (const float*)d_in[11], // b_out
      (const int*)d_in[12],   // n_chunks
      (float*)d_out);
}

// Round 4
// 8165.646 us; speedup vs baseline: 2.0186x; 1.1366x over previous
//
#include <hip/hip_runtime.h>

// PositionCloser round 4: MFMA restructure.
// 4 sequences per workgroup of 4 waves (256 WGs x 4 waves = 1024 waves, 1/SIMD).
// Per step: h(4x64) @ W_hh^T(64x256) via 8x mfma_f32_16x16x32_f16 per wave
// (wave w owns hid cols [16w,16w+16) across the 4 gates; B-frags live in 32
// VGPRs). h goes through double-buffered f16 LDS (1 barrier/step). MFMA C
// output (lanes 0-15) is redistributed via per-wave LDS scatter so each lane
// owns one (seq,hid) pair -> gate transcendentals spread over all 64 lanes.
// z = h.W_out via DPP row-reduce + cross-wave LDS partials, consumed lag-1.

#define CH   128
#define HID  64
#define HSTR 72   // hbuf row stride in halfs (64 + 8 pad -> 2-way banks only)

typedef __fp16 f16x8 __attribute__((ext_vector_type(8)));
typedef float  f32x4 __attribute__((ext_vector_type(4)));

#define MFMA16(a, b, c) __builtin_amdgcn_mfma_f32_16x16x32_f16((a), (b), (c), 0, 0, 0)

// DPP row_shr:k accumulate (16-lane rows); bound_ctrl=true -> OOB reads 0.
#define DPP_ADD(v, C) ((v) + __builtin_bit_cast(float, \
    __builtin_amdgcn_update_dpp(0, __builtin_bit_cast(int, (v)), (C), 0xF, 0xF, true)))

__device__ __forceinline__ float frcp(float x) { return __builtin_amdgcn_rcpf(x); }
__device__ __forceinline__ float sigm(float x) { return frcp(1.0f + __expf(-x)); }
__device__ __forceinline__ float tanh_(float x) {
  float e = __expf(2.0f * x);
  return 1.0f - 2.0f * frcp(e + 1.0f);
}

__global__ __launch_bounds__(256, 1)
void pc_lstm_kernel(const int* __restrict__ inds,
                    const float* __restrict__ p,
                    const float* __restrict__ ls_probs,
                    const float* __restrict__ open_probs,
                    const int* __restrict__ open_slices,
                    const float* __restrict__ open_hx,
                    const float* __restrict__ W_ih,
                    const float* __restrict__ W_hh,
                    const float* __restrict__ b_ih,
                    const float* __restrict__ b_hh,
                    const float* __restrict__ W_out,
                    const float* __restrict__ b_out,
                    const int* __restrict__ n_chunks_p,
                    float* __restrict__ out)
{
  __shared__ __align__(16) __fp16 hbuf[2][16 * HSTR];   // [parity][seq(16)][hid] (rows 4-15 stay 0)
  __shared__ __align__(16) float2 xbuf[2][4][CH];       // [chunk parity][seq][t] price deltas (f32)
  __shared__ __align__(16) float  ltbuf[2][4][CH];      // [chunk parity][seq][t] log p0 + log p1
  __shared__ __align__(16) float  zbuf[2][4][4];        // [step parity][seq][wave] z-partials
  __shared__ __align__(16) float  scat[4][4][16][4];    // [wave][gate][c][s] redistribute scratch

  const int tid  = threadIdx.x;
  const int w    = tid >> 6;         // wave 0..3
  const int lane = tid & 63;
  const int q    = lane >> 4;        // quad 0..3
  const int lm   = lane & 15;
  const int wg   = blockIdx.x;       // 0..255, seqs 4wg..4wg+3
  const int n_chunks = n_chunks_p[0];
  const int total = n_chunks * CH;

  // lane ownership for elementwise phase: (seq = q, hid = 16w + lm)
  const int hid_own = 16 * w + lm;
  const int sg_own  = wg * 4 + q;

  // ---- B fragments: wave w's gate-tiles, cols 16w..16w+16, K=64 in 2 halves.
  // B[k][n]: n = lane&15 (-> col 16w+lm = hid_own), k = kh*32 + q*8 + j.
  f16x8 Bf[4][2];
#pragma unroll
  for (int g = 0; g < 4; ++g)
#pragma unroll
    for (int kh = 0; kh < 2; ++kh) {
      const float* src = W_hh + (g * HID + hid_own) * HID + kh * 32 + q * 8;
      f16x8 b;
#pragma unroll
      for (int j = 0; j < 8; ++j) b[j] = (__fp16)src[j];
      Bf[g][kh] = b;
    }

  // per-lane input-weight/bias constants for its (hid_own) across 4 gates
  float wxa[4], wxb[4], bb[4];
#pragma unroll
  for (int g = 0; g < 4; ++g) {
    const int row = g * HID + hid_own;
    wxa[g] = W_ih[2 * row];
    wxb[g] = W_ih[2 * row + 1];
    bb[g]  = b_ih[row] + b_hh[row];
  }
  const float wo   = W_out[hid_own];
  const float bout = b_out[0];

  // ---- state: c in registers, h0 into hbuf[0]
  float cst = open_hx[(sg_own * 2 + 1) * HID + hid_own];
  const float h0 = open_hx[(sg_own * 2 + 0) * HID + hid_own];

  {
    __fp16* hb = &hbuf[0][0];
    for (int i = tid; i < 2 * 16 * HSTR; i += 256) hb[i] = (__fp16)0.0f;
  }
  __syncthreads();                       // zeroing before h0 stores
  hbuf[0][q * HSTR + hid_own] = (__fp16)h0;

  // refill params: lane covers seq q
  const int sg_q = wg * 4 + q;
  const int tb_q = inds[sg_q >> 4] + (sg_q & 15);

  // wave w handles loss for seq w
  const int   sg_w  = wg * 4 + w;
  const int   osw   = open_slices[sg_w];
  const float OLw   = __logf(p[2 * osw]) + __logf(p[2 * osw + 1]);
  const float coefw = open_probs[sg_w] * (2.0f * ls_probs[sg_w] - 1.0f);

  float Sd = 1.0f, Qd = 1.0f, lsum = 0.0f, psum = 0.0f;
  const float2* p2 = (const float2*)p;

  auto lagged_loss = [&](int lgt) {
    const int ltt = lgt & (CH - 1);
    const int lcb = (lgt >> 7) & 1;
    const float4 zz = *(const float4*)&zbuf[lgt & 1][w][0];
    const float pr = sigm(zz.x + zz.y + zz.z + zz.w + bout);
    const float Lt = ltbuf[lcb][w][ltt];
    if (ltt == 0) Qd = 1.0f;
    const float T  = (ltt == 0) ? 1.0f : Sd * Qd;   // t=0 prob undiscounted (ref quirk)
    const float pn = pr * T;
    lsum = fmaf(pn, Lt, lsum);
    psum += pn;
    if (ltt == CH - 1) Sd *= Qd;                    // carry excludes (1-p_last)
    Qd *= (1.0f - pr);
  };

  for (int gt = 0; gt < total; ++gt) {
    const int tt = gt & (CH - 1);
    const int cb = (gt >> 7) & 1;

    if (tt == 0) {
      // refill this chunk's x / log-p into LDS (wave w covers t in [32w,32w+32))
      const int tb2 = tb_q + (gt >> 7) * CH;
      const float2 pb = p2[tb2];               // chunk-base price of seq q
#pragma unroll
      for (int r = 0; r < 2; ++r) {
        const int t = 32 * w + 16 * r + lm;
        const float2 pt = p2[tb2 + t];
        float2 xv; xv.x = pt.x - pb.x; xv.y = pt.y - pb.y;
        xbuf[cb][q][t]  = xv;
        ltbuf[cb][q][t] = __logf(pt.x) + __logf(pt.y);
      }
      __syncthreads();
    }

    // A fragments from hbuf[gt&1]: A[m=lm][k = kh*32 + q*8 + j]
    const __fp16* hrow = &hbuf[gt & 1][lm * HSTR];
    const f16x8 a0 = *(const f16x8*)(hrow + q * 8);
    const f16x8 a1 = *(const f16x8*)(hrow + 32 + q * 8);

    // 8 MFMA: gates i,f,g,o for this wave's 16 hid cols
    f32x4 zero4 = {0.0f, 0.0f, 0.0f, 0.0f};
    f32x4 C0 = MFMA16(a0, Bf[0][0], zero4); C0 = MFMA16(a1, Bf[0][1], C0);
    f32x4 C1 = MFMA16(a0, Bf[1][0], zero4); C1 = MFMA16(a1, Bf[1][1], C1);
    f32x4 C2 = MFMA16(a0, Bf[2][0], zero4); C2 = MFMA16(a1, Bf[2][1], C2);
    f32x4 C3 = MFMA16(a0, Bf[3][0], zero4); C3 = MFMA16(a1, Bf[3][1], C3);

    // lag-1 loss for seq w (independent of this step's MFMA -> overlaps)
    if (gt > 0) lagged_loss(gt - 1);

    // redistribute C (valid rows 0-3 live in lanes 0-15, reg = seq):
    // lane c writes its 4 regs; lane (q,lm) reads (c=lm, s=q).
    if (lane < 16) {
      *(f32x4*)&scat[w][0][lane][0] = C0;
      *(f32x4*)&scat[w][1][lane][0] = C1;
      *(f32x4*)&scat[w][2][lane][0] = C2;
      *(f32x4*)&scat[w][3][lane][0] = C3;
    }
    const float2 xv = xbuf[cb][q][tt];
    float pa[4];
#pragma unroll
    for (int g = 0; g < 4; ++g) {
      const float cg = scat[w][g][lm][q];
      pa[g] = fmaf(xv.y, wxb[g], fmaf(xv.x, wxa[g], cg + bb[g]));
    }

    const float ig = sigm(pa[0]);
    const float fg = sigm(pa[1]);
    const float gg = tanh_(pa[2]);
    const float og = sigm(pa[3]);
    cst = fmaf(fg, cst, ig * gg);
    const float h = og * tanh_(cst);

    // h -> next step's A operand
    hbuf[(gt + 1) & 1][q * HSTR + hid_own] = (__fp16)h;

    // z partial: reduce h*wo over the 16 lanes of each seq-row via DPP
    float zp = h * wo;
    zp = DPP_ADD(zp, 0x111);
    zp = DPP_ADD(zp, 0x112);
    zp = DPP_ADD(zp, 0x114);
    zp = DPP_ADD(zp, 0x118);
    if (lm == 15) zbuf[gt & 1][q][w] = zp;

    __syncthreads();
  }

  lagged_loss(total - 1);   // drain the final step's loss

  if (lane == 0) atomicAdd(out, coefw * (lsum - OLw * psum));
}

extern "C" void kernel_launch(void* const* d_in, const int* in_sizes, int n_in,
                              void* d_out, int out_size, void* d_ws, size_t ws_size,
                              hipStream_t stream) {
  (void)hipMemsetAsync(d_out, 0, sizeof(float), stream);

  pc_lstm_kernel<<<dim3(256), dim3(256), 0, stream>>>(
      (const int*)d_in[0],    // inds
      (const float*)d_in[1],  // p
      (const float*)d_in[2],  // ls_probs
      (const float*)d_in[3],  // open_probs
      (const int*)d_in[4],    // open_slices
      (const float*)d_in[5],  // open_hx
      (const float*)d_in[6],  // W_ih
      (const float*)d_in[7],  // W_hh
      (const float*)d_in[8],  // b_ih
      (const float*)d_in[9],  // b_hh
      (const float*)d_in[10], // W_out
      (const float*)d_in[11], // b_out
      (const int*)d_in[12],   // n_chunks
      (float*)d_out);
}